// Round 12
// baseline (14702.594 us; speedup 1.0000x reference)
//
#include <hip/hip_runtime.h>

#define DEVINL __device__ __forceinline__

typedef unsigned short u16;
typedef __attribute__((ext_vector_type(8))) short bf16x8;   // 8 bf16 = 4 VGPRs (MFMA A/B frag)
typedef __attribute__((ext_vector_type(4))) float f32x4;     // MFMA C/D frag
typedef __attribute__((ext_vector_type(4))) unsigned short u16x4;

// B=4, S=1024, HID=4096, NH=32, NKV=8, HD=128, FF=11008

DEVINL float bf2f(u16 u) { union { unsigned i; float f; } x; x.i = ((unsigned)u) << 16; return x.f; }
DEVINL u16 f2bf(float f) {                       // round-to-nearest-even
  union { float f; unsigned i; } x; x.f = f;
  unsigned r = x.i + 0x7fffu + ((x.i >> 16) & 1u);
  return (u16)(r >> 16);
}

DEVINL void async16(u16* lds, const u16* g) {
  __builtin_amdgcn_global_load_lds((const __attribute__((address_space(1))) unsigned*)g,
                                   (__attribute__((address_space(3))) unsigned*)lds, 16, 0, 0);
}

struct CJob { const float* in; u16* out; int K, N, ntiles; int mode; };
// mode 0: out row = col index n (plain transpose)
// mode 1: gate-interleave: row = (n>>5)*64 + (n&31)
// mode 2: up-interleave:   row = (n>>5)*64 + 32 + (n&31)

// one 64x64 convert+transpose tile; 256 participating threads; 2 block-wide syncs
DEVINL void conv_one(const float* __restrict__ in, u16* __restrict__ out,
                     int K, int N, int tile, int t, float (*tl)[65], int mode) {
  int tn = N >> 6;
  int kt = tile / tn;
  int k0 = kt << 6, n0 = (tile - kt*tn) << 6;
  int r = t >> 4, c4 = (t & 15) << 2;
  #pragma unroll
  for (int it = 0; it < 4; it++) {
    int row = r + it*16;
    f32x4 v = *(const f32x4*)(in + (size_t)(k0 + row)*N + n0 + c4);
    tl[row][c4+0] = v[0]; tl[row][c4+1] = v[1];
    tl[row][c4+2] = v[2]; tl[row][c4+3] = v[3];
  }
  __syncthreads();
  #pragma unroll
  for (int it = 0; it < 4; it++) {
    int nrow = r + it*16;
    u16x4 ov;
    #pragma unroll
    for (int e = 0; e < 4; e++) ov[e] = f2bf(tl[c4+e][nrow]);
    int orow = n0 + nrow;
    if (mode == 1)      orow = ((orow >> 5) << 6) + (orow & 31);
    else if (mode == 2) orow = ((orow >> 5) << 6) + 32 + (orow & 31);
    *(u16x4*)(out + (size_t)orow*K + k0 + c4) = ov;
  }
  __syncthreads();
}

// ---------------- standalone conv (QKV), grid-stride over 3 jobs ----------------
__global__ __launch_bounds__(256) void conv3(CJob j0, CJob j1, CJob j2) {
  __shared__ float tl[64][65];
  int ntot = j0.ntiles + j1.ntiles + j2.ntiles;
  for (int g = blockIdx.x; g < ntot; g += gridDim.x) {
    CJob* jp;
    int tile;
    if (g < j0.ntiles)                 { jp = &j0; tile = g; }
    else if (g < j0.ntiles + j1.ntiles){ jp = &j1; tile = g - j0.ntiles; }
    else                               { jp = &j2; tile = g - j0.ntiles - j1.ntiles; }
    conv_one(jp->in, jp->out, jp->K, jp->N, tile, threadIdx.x, tl, jp->mode);
  }
}

// ---------------- RMSNorm: fp32 in [4096 rows x 4096] -> bf16 out ----------------
__global__ __launch_bounds__(256) void rmsnorm_kernel(const float* __restrict__ x,
                                                      const float* __restrict__ w,
                                                      u16* __restrict__ out) {
  int row = blockIdx.x, t = threadIdx.x;
  const float* xr = x + (size_t)row * 4096;
  f32x4 v[4];
  float ss = 0.f;
  #pragma unroll
  for (int i = 0; i < 4; i++) {
    v[i] = *(const f32x4*)(xr + (t + 256*i)*4);
    ss += v[i][0]*v[i][0] + v[i][1]*v[i][1] + v[i][2]*v[i][2] + v[i][3]*v[i][3];
  }
  #pragma unroll
  for (int d = 1; d < 64; d <<= 1) ss += __shfl_xor(ss, d, 64);
  __shared__ float ps[4];
  if ((t & 63) == 0) ps[t >> 6] = ss;
  __syncthreads();
  float scale = rsqrtf((ps[0]+ps[1]+ps[2]+ps[3]) * (1.f/4096.f) + 1e-6f);
  #pragma unroll
  for (int i = 0; i < 4; i++) {
    f32x4 wv = *(const f32x4*)(w + (t + 256*i)*4);
    u16x4 o;
    #pragma unroll
    for (int e = 0; e < 4; e++) o[e] = f2bf(v[i][e] * scale * wv[e]);
    *(u16x4*)(out + (size_t)row*4096 + (t + 256*i)*4) = o;
  }
}

// ---------------- RoPE in-place on q [tok,4096] & k [tok, kstr]; q gets 1/sqrt(HD) ----------------
__global__ __launch_bounds__(256) void rope_kernel(u16* __restrict__ q, u16* __restrict__ k, int kstr) {
  int tok = blockIdx.x;
  int s = tok & 1023;
  __shared__ float cs[64], sn[64];
  int t = threadIdx.x;
  if (t < 64) {
    float inv = __expf(-(float)t * 0.14391156934f);
    float ang = (float)s * inv;
    cs[t] = cosf(ang); sn[t] = sinf(ang);
  }
  __syncthreads();
  const float qscale = 0.08838834764831845f;
  size_t qbase = (size_t)tok * 4096;
  #pragma unroll
  for (int it = 0; it < 8; it++) {
    int item = t + it*256; int h = item >> 6, j = item & 63;
    size_t i0 = qbase + h*128 + j;
    float x1 = bf2f(q[i0]), x2 = bf2f(q[i0+64]);
    float c = cs[j], si = sn[j];
    q[i0]    = f2bf((x1*c - x2*si) * qscale);
    q[i0+64] = f2bf((x2*c + x1*si) * qscale);
  }
  size_t kbase = (size_t)tok * kstr;
  #pragma unroll
  for (int it = 0; it < 2; it++) {
    int item = t + it*256; int h = item >> 6, j = item & 63;
    size_t i0 = kbase + h*128 + j;
    float x1 = bf2f(k[i0]), x2 = bf2f(k[i0+64]);
    float c = cs[j], si = sn[j];
    k[i0]    = f2bf(x1*c - x2*si);
    k[i0+64] = f2bf(x2*c + x1*si);
  }
}

// ---------------- V transpose per (b,kvh): [1024 x 128] (stride vstr) -> vt [128 x 1024] ----------------
__global__ __launch_bounds__(256) void vtrans(const u16* __restrict__ v, u16* __restrict__ vt, int vstr) {
  __shared__ u16 tile[32][33];
  int bh = blockIdx.z; int b = bh >> 3, kvh = bh & 7;
  int d0 = blockIdx.x << 5, s0 = blockIdx.y << 5;
  int tx = threadIdx.x, ty = threadIdx.y;
  for (int r = ty; r < 32; r += 8)
    tile[r][tx] = v[(size_t)(b*1024 + s0 + r)*vstr + kvh*128 + d0 + tx];
  __syncthreads();
  for (int r = ty; r < 32; r += 8)
    vt[(size_t)((b*8 + kvh)*128 + d0 + r)*1024 + s0 + tx] = tile[tx][r];
}

// ---------------- 128-tile GEMM (merged K+V projection) ----------------
template<int EPI>
__global__ __launch_bounds__(256, 2) void gemm_bt(
    const u16* __restrict__ A, const u16* __restrict__ Bt,
    void* __restrict__ Cv, const float* __restrict__ resid,
    const u16* __restrict__ gate, int M, int N, int K) {
  __shared__ u16 As[128*64];
  __shared__ u16 Bs[128*64];
  int nwg = gridDim.x;
  int bid = (int)blockIdx.x;
  int cpx = nwg >> 3;
  int swz = (bid & 7) * cpx + (bid >> 3);
  int mt = M >> 7;
  int m0 = (swz % mt) << 7;
  int n0 = (swz / mt) << 7;
  int tid = threadIdx.x;
  int lane = tid & 63, wave = tid >> 6;
  int wm = wave >> 1, wn = wave & 1;

  f32x4 acc[4][4];
  f32x4 zero = {0.f, 0.f, 0.f, 0.f};
  #pragma unroll
  for (int i = 0; i < 4; i++)
    #pragma unroll
    for (int j = 0; j < 4; j++) acc[i][j] = zero;

  int arow[4], acolb[4];
  #pragma unroll
  for (int i = 0; i < 4; i++) {
    int c = i*256 + tid;
    arow[i]  = c >> 3;
    acolb[i] = ((c & 7) * 16) ^ ((arow[i] & 7) << 4);
  }

  int nsteps = K >> 6;
  for (int t = 0; t < nsteps; t++) {
    int k0 = t << 6;
    #pragma unroll
    for (int i = 0; i < 4; i++) {
      async16(As + i*2048 + wave*512, A  + (size_t)(m0 + arow[i])*K + k0 + (acolb[i] >> 1));
      async16(Bs + i*2048 + wave*512, Bt + (size_t)(n0 + arow[i])*K + k0 + (acolb[i] >> 1));
    }
    __syncthreads();
    #pragma unroll
    for (int ks = 0; ks < 2; ks++) {
      bf16x8 af[4], bfr[4];
      int c2 = (ks*32 + (lane >> 4)*8) * 2;
      #pragma unroll
      for (int mf = 0; mf < 4; mf++) {
        int r = wm*64 + mf*16 + (lane & 15);
        af[mf] = *(const bf16x8*)(As + r*64 + ((c2 ^ ((r & 7) << 4)) >> 1));
      }
      #pragma unroll
      for (int nf = 0; nf < 4; nf++) {
        int r = wn*64 + nf*16 + (lane & 15);
        bfr[nf] = *(const bf16x8*)(Bs + r*64 + ((c2 ^ ((r & 7) << 4)) >> 1));
      }
      #pragma unroll
      for (int mf = 0; mf < 4; mf++)
        #pragma unroll
        for (int nf = 0; nf < 4; nf++)
          acc[mf][nf] = __builtin_amdgcn_mfma_f32_16x16x32_bf16(af[mf], bfr[nf], acc[mf][nf], 0, 0, 0);
    }
    __syncthreads();
  }

  #pragma unroll
  for (int mf = 0; mf < 4; mf++)
    #pragma unroll
    for (int nf = 0; nf < 4; nf++)
      #pragma unroll
      for (int j = 0; j < 4; j++) {
        int rr = m0 + wm*64 + mf*16 + (lane >> 4)*4 + j;
        int cc = n0 + wn*64 + nf*16 + (lane & 15);
        size_t idx = (size_t)rr * N + cc;
        float v = acc[mf][nf][j];
        if constexpr (EPI == 0) {
          ((u16*)Cv)[idx] = f2bf(v);
        } else if constexpr (EPI == 1) {
          ((float*)Cv)[idx] = v + resid[idx];
        } else {
          float g = bf2f(gate[idx]);
          float sg = g / (1.f + __expf(-g));
          ((u16*)Cv)[idx] = f2bf(sg * v);
        }
      }
}

// ---------------- 256x256 GEMM: SINGLE-buffer, 64 KiB LDS, 2 blocks/CU ----------
// Mechanism: all operands are read into registers (24 b128/wave) BEFORE any MFMA, so after the
// lgkm drain the buffer is dead -> stage(t+1) is issued immediately and its flight hides under
// the 64 register-only MFMAs. With 64 KiB LDS, TWO blocks co-reside per CU (16 waves/CU): one
// block's LDS-read phase overlaps the other's MFMA phase (complementary pipes, m114).
// Race-free: only full-drain __syncthreads (vmcnt0+lgkmcnt0+barrier), 2 per K-tile.
// EPI: 0 = bf16 C; 1 = fp32 C + resid; 3 = interleaved gate/up -> act = silu(g)*u, [M][11008] bf16.
#define MFMAQ(qm, qn, AF, BQ) do { \
  __builtin_amdgcn_s_setprio(1); \
  _Pragma("unroll") for (int mf_ = 0; mf_ < 4; mf_++) \
  _Pragma("unroll") for (int nf_ = 0; nf_ < 2; nf_++) \
  _Pragma("unroll") for (int ks_ = 0; ks_ < 2; ks_++) \
    acc[(qm)*4+mf_][(qn)*2+nf_] = __builtin_amdgcn_mfma_f32_16x16x32_bf16( \
        AF[mf_][ks_], BQ[nf_][ks_], acc[(qm)*4+mf_][(qn)*2+nf_], 0, 0, 0); \
  __builtin_amdgcn_s_setprio(0); } while (0)

template<int KC, int EPI>
__global__ __launch_bounds__(512, 4) void gemm256(
    const u16* __restrict__ A, const u16* __restrict__ Bt,
    void* __restrict__ Cv, const float* __restrict__ resid,
    int M, int N, int G,
    const float* __restrict__ cvin, u16* __restrict__ cvout, int cvK, int cvN, int cvTiles, int cvMode) {
  extern __shared__ u16 lds[];                  // single buffer: A 32KB | B 32KB = 64 KiB
  int bid = (int)blockIdx.x;
  int tid = threadIdx.x;

  if (bid >= G) {                               // hosted conv blocks (2 x 16.9KB tiles <= 64KB)
    int cb = bid - G, CB = (int)gridDim.x - G;
    int h = tid >> 8, t = tid & 255;
    float (*tl)[65] = (float(*)[65])((char*)lds + h*16896);
    int pairs = cvTiles >> 1;
    for (int p = cb; p < pairs; p += CB)
      conv_one(cvin, cvout, cvK, cvN, 2*p + h, t, tl, cvMode);
    return;
  }

  int cpx = G >> 3;
  int swz = (bid & 7) * cpx + (bid >> 3);       // XCD swizzle (T1); G % 8 == 0
  int mt = M >> 8;
  int m0 = (swz % mt) << 8;
  int n0 = (swz / mt) << 8;
  int lane = tid & 63, wave = tid >> 6;
  int wm = wave >> 2, wn = wave & 3;

  f32x4 acc[8][4];
  f32x4 zero = {0.f, 0.f, 0.f, 0.f};
  #pragma unroll
  for (int i = 0; i < 8; i++)
    #pragma unroll
    for (int j = 0; j < 4; j++) acc[i][j] = zero;

  // staging addresses (global pre-swizzled, LDS linear — rule #21)
  int sCol = ((lane & 7) ^ (lane >> 3)) << 3;
  int aRow = (wave >> 2)*128 + (wave & 3)*16 + (lane >> 3);
  int bRow = (wave >> 1)*64  + (wave & 1)*16 + (lane >> 3);
  const u16* gA = A  + (size_t)(m0 + aRow) * KC + sCol;
  const u16* gB = Bt + (size_t)(n0 + bRow) * KC + sCol;
  constexpr size_t K8 = (size_t)8 * KC, K32 = (size_t)32 * KC, K64 = (size_t)64 * KC;

  // fragment read offsets: stored chunk = logical ^ (row&7)
  int rA = lane & 15;
  int acol0 = (((lane >> 4)    ) ^ (rA & 7)) << 3;
  int acol1 = (((lane >> 4) + 4) ^ (rA & 7)) << 3;

  bf16x8 afA[4][2], afB[4][2], b0[2][2], b1[2][2];

  auto stageAq = [&](int qm, int k0) {
    u16* d = lds + qm*8192 + wave*1024;
    const u16* s = gA + (size_t)qm*K64 + k0;
    async16(d, s); async16(d + 512, s + K8);
  };
  auto stageBq = [&](int qn, int k0) {
    u16* d = lds + 16384 + qn*8192 + wave*1024;
    const u16* s = gB + (size_t)qn*K32 + k0;
    async16(d, s); async16(d + 512, s + K8);
  };
  auto stageAll = [&](int k0) {
    stageAq(0, k0); stageAq(1, k0);
    stageBq(0, k0); stageBq(1, k0);
  };
  auto loadAq = [&](int qm, bf16x8 (&af)[4][2]) {
    const u16* base = lds + qm*8192 + wm*4096 + rA*64;
    #pragma unroll
    for (int mf = 0; mf < 4; mf++) {
      af[mf][0] = *(const bf16x8*)(base + mf*1024 + acol0);
      af[mf][1] = *(const bf16x8*)(base + mf*1024 + acol1);
    }
  };
  auto loadBq = [&](int qn, bf16x8 (&bq)[2][2]) {
    const u16* base = lds + 16384 + qn*8192 + wn*2048 + rA*64;
    #pragma unroll
    for (int nf = 0; nf < 2; nf++) {
      bq[nf][0] = *(const bf16x8*)(base + nf*1024 + acol0);
      bq[nf][1] = *(const bf16x8*)(base + nf*1024 + acol1);
    }
  };

  constexpr int nt = KC >> 6;
  stageAll(0);
  __syncthreads();                              // tile 0 landed (full drain)
  #pragma unroll 1
  for (int t = 0; t < nt; t++) {
    // 1) pull ALL operands into registers (24 x ds_read_b128 per wave)
    loadAq(0, afA); loadBq(0, b0); loadBq(1, b1); loadAq(1, afB);
    __syncthreads();                            // lgkm drained: buffer dead, all waves done reading
    // 2) stage next tile into the (now-dead) buffer; flight hides under the MFMAs below
    if (t + 1 < nt) stageAll((t + 1) << 6);
    // 3) 64 register-only MFMAs
    MFMAQ(0, 0, afA, b0);
    MFMAQ(0, 1, afA, b1);
    MFMAQ(1, 0, afB, b0);
    MFMAQ(1, 1, afB, b1);
    __syncthreads();                            // vm drained: next tile landed for everyone
  }

  if constexpr (EPI == 3) {
    // acc[mf][nf] (nf=0,1) = gate, acc[mf][nf+2] = up, SAME output column (in-thread pairing)
    int colb = (n0 >> 1) + wn*32 + (lane & 15);
    #pragma unroll
    for (int mf = 0; mf < 8; mf++)
      #pragma unroll
      for (int nf = 0; nf < 2; nf++)
        #pragma unroll
        for (int j = 0; j < 4; j++) {
          int rr = m0 + wm*128 + mf*16 + (lane >> 4)*4 + j;
          float g = acc[mf][nf][j];
          float u = acc[mf][nf+2][j];
          float sg = g / (1.f + __expf(-g));
          ((u16*)Cv)[(size_t)rr * 11008 + colb + nf*16] = f2bf(sg * u);
        }
  } else {
    #pragma unroll
    for (int mf = 0; mf < 8; mf++)
      #pragma unroll
      for (int nf = 0; nf < 4; nf++)
        #pragma unroll
        for (int j = 0; j < 4; j++) {
          int rr = m0 + wm*128 + mf*16 + (lane >> 4)*4 + j;
          int cc = n0 + wn*64 + nf*16 + (lane & 15);
          size_t idx = (size_t)rr * N + cc;
          float v = acc[mf][nf][j];
          if constexpr (EPI == 0) {
            ((u16*)Cv)[idx] = f2bf(v);
          } else if constexpr (EPI == 1) {
            ((float*)Cv)[idx] = v + resid[idx];
          }
        }
  }
}

// ---------------- Flash attention, causal, GQA 4:1 (+ hosted weight-conversion blocks) ----------------
__global__ __launch_bounds__(256, 4) void attn_kernel(
    const u16* __restrict__ q, const u16* __restrict__ k,
    const u16* __restrict__ vt, u16* __restrict__ out,
    CJob j0, CJob j1, CJob j2, int kstr) {
  __shared__ __align__(16) u16 shm[20480];      // 40 KB: Ks 16K | Vs 16K | Ps 8K
  u16* Ks = shm;
  u16* Vs = shm + 8192;
  u16* Ps = shm + 16384;
  int bid = blockIdx.x;

  if (bid >= 2048) {                            // hosted conv blocks
    int cb = bid - 2048, CB = (int)gridDim.x - 2048;
    float (*tl)[65] = (float(*)[65])shm;
    int ntot = j0.ntiles + j1.ntiles + j2.ntiles;
    for (int g = cb; g < ntot; g += CB) {
      CJob* jp; int tile;
      if (g < j0.ntiles)                  { jp = &j0; tile = g; }
      else if (g < j0.ntiles + j1.ntiles) { jp = &j1; tile = g - j0.ntiles; }
      else                                { jp = &j2; tile = g - j0.ntiles - j1.ntiles; }
      conv_one(jp->in, jp->out, jp->K, jp->N, tile, threadIdx.x, tl, jp->mode);
    }
    return;
  }

  int qt = bid & 15;
  int h  = (bid >> 4) & 31;
  int b  = bid >> 9;
  int kvh = h >> 2;
  int tid = threadIdx.x, lane = tid & 63, wave = tid >> 6;
  int q0 = qt << 6;

  bf16x8 qf[4];
  {
    const u16* qb_ = q + (size_t)(b*1024 + q0 + wave*16 + (lane & 15))*4096 + h*128 + (lane >> 4)*8;
    #pragma unroll
    for (int ks = 0; ks < 4; ks++) qf[ks] = *(const bf16x8*)(qb_ + ks*32);
  }
  f32x4 o[8];
  f32x4 zero = {0.f,0.f,0.f,0.f};
  #pragma unroll
  for (int i = 0; i < 8; i++) o[i] = zero;
  float m[4] = {-1e30f,-1e30f,-1e30f,-1e30f};
  float l[4] = {0.f,0.f,0.f,0.f};

  int kr[4], kc[4], vr[4], vc[4];
  #pragma unroll
  for (int i = 0; i < 4; i++) {
    int c = i*256 + tid;
    kr[i] = c >> 4; kc[i] = ((c & 15)*16) ^ ((kr[i] & 7) << 4);
    vr[i] = c >> 3; vc[i] = ((c & 7)*16)  ^ ((vr[i] & 7) << 4);
  }

  for (int t = 0; t <= qt; t++) {
    int kv0 = t << 6;
    #pragma unroll
    for (int i = 0; i < 4; i++) {
      async16(Ks + i*2048 + wave*512, k  + (size_t)(b*1024 + kv0 + kr[i])*kstr + kvh*128 + (kc[i] >> 1));
      async16(Vs + i*2048 + wave*512, vt + (size_t)((b*8 + kvh)*128 + vr[i])*1024 + kv0 + (vc[i] >> 1));
    }
    __syncthreads();

    f32x4 s[4];
    #pragma unroll
    for (int nf = 0; nf < 4; nf++) {
      s[nf] = zero;
      #pragma unroll
      for (int ks = 0; ks < 4; ks++) {
        int r = nf*16 + (lane & 15);
        int c2 = (ks*32 + (lane >> 4)*8)*2;
        bf16x8 kf = *(const bf16x8*)(Ks + r*128 + ((c2 ^ ((r & 7) << 4)) >> 1));
        s[nf] = __builtin_amdgcn_mfma_f32_16x16x32_bf16(qf[ks], kf, s[nf], 0, 0, 0);
      }
    }
    if (t == qt) {
      #pragma unroll
      for (int nf = 0; nf < 4; nf++)
        #pragma unroll
        for (int j = 0; j < 4; j++) {
          int cc = nf*16 + (lane & 15);
          int rr = wave*16 + (lane >> 4)*4 + j;
          if (cc > rr) s[nf][j] = -1e30f;
        }
    }
    #pragma unroll
    for (int j = 0; j < 4; j++) {
      float mx = fmaxf(fmaxf(s[0][j], s[1][j]), fmaxf(s[2][j], s[3][j]));
      #pragma unroll
      for (int d = 1; d < 16; d <<= 1) mx = fmaxf(mx, __shfl_xor(mx, d, 64));
      float mn = fmaxf(m[j], mx);
      float f = __expf(m[j] - mn);
      m[j] = mn;
      float ssum = 0.f;
      #pragma unroll
      for (int nf = 0; nf < 4; nf++) {
        float p = __expf(s[nf][j] - mn);
        s[nf][j] = p; ssum += p;
      }
      #pragma unroll
      for (int d = 1; d < 16; d <<= 1) ssum += __shfl_xor(ssum, d, 64);
      l[j] = l[j]*f + ssum;
      #pragma unroll
      for (int nf = 0; nf < 8; nf++) o[nf][j] *= f;
    }
    #pragma unroll
    for (int nf = 0; nf < 4; nf++)
      #pragma unroll
      for (int j = 0; j < 4; j++) {
        int rr = (lane >> 4)*4 + j;
        int cb2 = ((nf*16 + (lane & 15))*2) ^ ((rr & 7) << 4);
        Ps[wave*1024 + rr*64 + (cb2 >> 1)] = f2bf(s[nf][j]);
      }
    #pragma unroll
    for (int ks2 = 0; ks2 < 2; ks2++) {
      int mr = lane & 15;
      int c2 = (ks2*32 + (lane >> 4)*8)*2;
      bf16x8 pa = *(const bf16x8*)(Ps + wave*1024 + mr*64 + ((c2 ^ ((mr & 7) << 4)) >> 1));
      #pragma unroll
      for (int nf = 0; nf < 8; nf++) {
        int d = nf*16 + (lane & 15);
        bf16x8 vf = *(const bf16x8*)(Vs + d*64 + ((c2 ^ ((d & 7) << 4)) >> 1));
        o[nf] = __builtin_amdgcn_mfma_f32_16x16x32_bf16(pa, vf, o[nf], 0, 0, 0);
      }
    }
    __syncthreads();
  }

  float inv[4];
  #pragma unroll
  for (int j = 0; j < 4; j++) inv[j] = 1.f / l[j];
  u16* ob = out + (size_t)(b*1024 + q0 + wave*16)*4096 + h*128;
  #pragma unroll
  for (int nf = 0; nf < 8; nf++)
    #pragma unroll
    for (int j = 0; j < 4; j++) {
      int rr = (lane >> 4)*4 + j;
      int cc = nf*16 + (lane & 15);
      ob[(size_t)rr*4096 + cc] = f2bf(o[nf][j] * inv[j]);
    }
}

// ---------------- driver ----------------
extern "C" void kernel_launch(void* const* d_in, const int* in_sizes, int n_in,
                              void* d_out, int out_size, void* d_ws, size_t ws_size,
                              hipStream_t stream) {
  (void)in_sizes; (void)n_in; (void)out_size;
  const float* hidden = (const float*)d_in[0];
  const float* Wq  = (const float*)d_in[3];
  const float* Wk  = (const float*)d_in[4];
  const float* Wv  = (const float*)d_in[5];
  const float* Wo  = (const float*)d_in[6];
  const float* ln1 = (const float*)d_in[7];
  const float* ln2 = (const float*)d_in[8];
  const float* Wg  = (const float*)d_in[9];
  const float* Wu  = (const float*)d_in[10];
  const float* Wd  = (const float*)d_in[11];
  float* out = (float*)d_out;

  hipFuncSetAttribute((const void*)gemm256<4096,0>,  hipFuncAttributeMaxDynamicSharedMemorySize, 65536);
  hipFuncSetAttribute((const void*)gemm256<4096,1>,  hipFuncAttributeMaxDynamicSharedMemorySize, 65536);
  hipFuncSetAttribute((const void*)gemm256<4096,3>,  hipFuncAttributeMaxDynamicSharedMemorySize, 65536);
  hipFuncSetAttribute((const void*)gemm256<11008,1>, hipFuncAttributeMaxDynamicSharedMemorySize, 65536);

  char* ws = (char*)d_ws;
  size_t off = 0;
  auto alloc = [&](size_t b) { char* p = ws + off; off += (b + 4095) & ~(size_t)4095; return p; };

  u16*  wqkvT = (u16*)alloc(50331648);   // [6144][4096] bf16: wq | wk | wv
  u16*  woT   = (u16*)alloc(33554432);
  (void)alloc(8388608);                  // pad: lets wdT (86 MiB) alias wqkvT+woT+pad
  u16*  wguT  = (u16*)alloc(180355072);  // [22016][4096] interleaved gate/up (64-row = 32g+32u)
  u16*  h1    = (u16*)alloc(33554432);
  u16*  qb    = (u16*)alloc(33554432);
  u16*  kvb   = (u16*)alloc(16777216);   // [4096 tok][2048]: k | v
  u16*  vtb   = (u16*)alloc(8388608);
  float* hmid = (float*)alloc(67108864);
  u16*  gb    = (u16*)alloc(90177536);   // act [4096][11008] bf16
  if (off > ws_size) return;             // ws too small -> fail visibly

  u16* wqT  = wqkvT;
  u16* wkvT = wqkvT + 16777216;
  u16* wkT  = wkvT;
  u16* wvT  = wkvT + 4194304;
  u16* wdT  = wqkvT;                     // aliases wqkvT+woT+pad, both dead by gateup time
  CJob Jq{Wq, wqT, 4096, 4096, 4096, 0}, Jk{Wk, wkT, 4096, 1024, 1024, 0}, Jv{Wv, wvT, 4096, 1024, 1024, 0};
  CJob Jo{Wo, woT, 4096, 4096, 4096, 0};
  CJob Jg{Wg, wguT, 4096, 11008, 11008, 1}, Ju{Wu, wguT, 4096, 11008, 11008, 2};

  dim3 blk(256);
  conv3<<<2048, blk, 0, stream>>>(Jq, Jk, Jv);
  rmsnorm_kernel<<<4096, blk, 0, stream>>>(hidden, ln1, h1);
  gemm256<4096,0><<<256, 512, 65536, stream>>>(h1, wqT, qb, nullptr, 4096, 4096, 256,
                                               nullptr, nullptr, 0, 0, 0, 0);
  gemm_bt<0><<<512, blk, 0, stream>>>(h1, wkvT, kvb, nullptr, nullptr, 4096, 2048, 4096);
  rope_kernel<<<4096, blk, 0, stream>>>(qb, kvb, 2048);
  vtrans<<<dim3(4, 32, 32), dim3(32, 8), 0, stream>>>(kvb + 1024, vtb, 2048);
  // attention + hosted conversions of Wo (plain), Wg/Wu (interleaved into wguT)
  attn_kernel<<<2048 + 1024, blk, 0, stream>>>(qb, kvb, vtb, h1, Jo, Jg, Ju, 2048);
  gemm256<4096,1><<<256, 512, 65536, stream>>>(h1, woT, hmid, hidden, 4096, 4096, 256,
                                               nullptr, nullptr, 0, 0, 0, 0);
  rmsnorm_kernel<<<4096, blk, 0, stream>>>(hmid, ln2, qb);
  // merged gate+up GEMM (N-rows 22016 -> act [4096][11008]) + hosted Wd conversion
  gemm256<4096,3><<<1376 + 344, 512, 65536, stream>>>(qb, wguT, gb, nullptr, 4096, 11008, 1376,
                                                      Wd, wdT, 11008, 4096, 11008, 0);
  gemm256<11008,1><<<256, 512, 65536, stream>>>(gb, wdT, out, hmid, 4096, 4096, 256,
                                                nullptr, nullptr, 0, 0, 0, 0);
}

// Round 13
// 1738.226 us; speedup vs baseline: 8.4584x; 8.4584x over previous
//
#include <hip/hip_runtime.h>

#define DEVINL __device__ __forceinline__

typedef unsigned short u16;
typedef __attribute__((ext_vector_type(8))) short bf16x8;   // 8 bf16 = 4 VGPRs (MFMA A/B frag)
typedef __attribute__((ext_vector_type(4))) float f32x4;     // MFMA C/D frag
typedef __attribute__((ext_vector_type(4))) unsigned short u16x4;

// B=4, S=1024, HID=4096, NH=32, NKV=8, HD=128, FF=11008

DEVINL float bf2f(u16 u) { union { unsigned i; float f; } x; x.i = ((unsigned)u) << 16; return x.f; }
DEVINL u16 f2bf(float f) {                       // round-to-nearest-even
  union { float f; unsigned i; } x; x.f = f;
  unsigned r = x.i + 0x7fffu + ((x.i >> 16) & 1u);
  return (u16)(r >> 16);
}

DEVINL void async16(u16* lds, const u16* g) {
  __builtin_amdgcn_global_load_lds((const __attribute__((address_space(1))) unsigned*)g,
                                   (__attribute__((address_space(3))) unsigned*)lds, 16, 0, 0);
}

struct CJob { const float* in; u16* out; int K, N, ntiles; int mode; };
// mode 0: out row = col index n (plain transpose)
// mode 1: gate-interleave: row = (n>>5)*64 + (n&31)
// mode 2: up-interleave:   row = (n>>5)*64 + 32 + (n&31)

// one 64x64 convert+transpose tile; 256 participating threads; 2 block-wide syncs
DEVINL void conv_one(const float* __restrict__ in, u16* __restrict__ out,
                     int K, int N, int tile, int t, float (*tl)[65], int mode) {
  int tn = N >> 6;
  int kt = tile / tn;
  int k0 = kt << 6, n0 = (tile - kt*tn) << 6;
  int r = t >> 4, c4 = (t & 15) << 2;
  #pragma unroll
  for (int it = 0; it < 4; it++) {
    int row = r + it*16;
    f32x4 v = *(const f32x4*)(in + (size_t)(k0 + row)*N + n0 + c4);
    tl[row][c4+0] = v[0]; tl[row][c4+1] = v[1];
    tl[row][c4+2] = v[2]; tl[row][c4+3] = v[3];
  }
  __syncthreads();
  #pragma unroll
  for (int it = 0; it < 4; it++) {
    int nrow = r + it*16;
    u16x4 ov;
    #pragma unroll
    for (int e = 0; e < 4; e++) ov[e] = f2bf(tl[c4+e][nrow]);
    int orow = n0 + nrow;
    if (mode == 1)      orow = ((orow >> 5) << 6) + (orow & 31);
    else if (mode == 2) orow = ((orow >> 5) << 6) + 32 + (orow & 31);
    *(u16x4*)(out + (size_t)orow*K + k0 + c4) = ov;
  }
  __syncthreads();
}

// ---------------- standalone conv (QKV), grid-stride over 3 jobs ----------------
__global__ __launch_bounds__(256) void conv3(CJob j0, CJob j1, CJob j2) {
  __shared__ float tl[64][65];
  int ntot = j0.ntiles + j1.ntiles + j2.ntiles;
  for (int g = blockIdx.x; g < ntot; g += gridDim.x) {
    CJob* jp;
    int tile;
    if (g < j0.ntiles)                 { jp = &j0; tile = g; }
    else if (g < j0.ntiles + j1.ntiles){ jp = &j1; tile = g - j0.ntiles; }
    else                               { jp = &j2; tile = g - j0.ntiles - j1.ntiles; }
    conv_one(jp->in, jp->out, jp->K, jp->N, tile, threadIdx.x, tl, jp->mode);
  }
}

// ---------------- RMSNorm: fp32 in [4096 rows x 4096] -> bf16 out ----------------
__global__ __launch_bounds__(256) void rmsnorm_kernel(const float* __restrict__ x,
                                                      const float* __restrict__ w,
                                                      u16* __restrict__ out) {
  int row = blockIdx.x, t = threadIdx.x;
  const float* xr = x + (size_t)row * 4096;
  f32x4 v[4];
  float ss = 0.f;
  #pragma unroll
  for (int i = 0; i < 4; i++) {
    v[i] = *(const f32x4*)(xr + (t + 256*i)*4);
    ss += v[i][0]*v[i][0] + v[i][1]*v[i][1] + v[i][2]*v[i][2] + v[i][3]*v[i][3];
  }
  #pragma unroll
  for (int d = 1; d < 64; d <<= 1) ss += __shfl_xor(ss, d, 64);
  __shared__ float ps[4];
  if ((t & 63) == 0) ps[t >> 6] = ss;
  __syncthreads();
  float scale = rsqrtf((ps[0]+ps[1]+ps[2]+ps[3]) * (1.f/4096.f) + 1e-6f);
  #pragma unroll
  for (int i = 0; i < 4; i++) {
    f32x4 wv = *(const f32x4*)(w + (t + 256*i)*4);
    u16x4 o;
    #pragma unroll
    for (int e = 0; e < 4; e++) o[e] = f2bf(v[i][e] * scale * wv[e]);
    *(u16x4*)(out + (size_t)row*4096 + (t + 256*i)*4) = o;
  }
}

// ---------------- RoPE in-place on q [tok,4096] & k [tok, kstr]; q gets 1/sqrt(HD) ----------------
__global__ __launch_bounds__(256) void rope_kernel(u16* __restrict__ q, u16* __restrict__ k, int kstr) {
  int tok = blockIdx.x;
  int s = tok & 1023;
  __shared__ float cs[64], sn[64];
  int t = threadIdx.x;
  if (t < 64) {
    float inv = __expf(-(float)t * 0.14391156934f);
    float ang = (float)s * inv;
    cs[t] = cosf(ang); sn[t] = sinf(ang);
  }
  __syncthreads();
  const float qscale = 0.08838834764831845f;
  size_t qbase = (size_t)tok * 4096;
  #pragma unroll
  for (int it = 0; it < 8; it++) {
    int item = t + it*256; int h = item >> 6, j = item & 63;
    size_t i0 = qbase + h*128 + j;
    float x1 = bf2f(q[i0]), x2 = bf2f(q[i0+64]);
    float c = cs[j], si = sn[j];
    q[i0]    = f2bf((x1*c - x2*si) * qscale);
    q[i0+64] = f2bf((x2*c + x1*si) * qscale);
  }
  size_t kbase = (size_t)tok * kstr;
  #pragma unroll
  for (int it = 0; it < 2; it++) {
    int item = t + it*256; int h = item >> 6, j = item & 63;
    size_t i0 = kbase + h*128 + j;
    float x1 = bf2f(k[i0]), x2 = bf2f(k[i0+64]);
    float c = cs[j], si = sn[j];
    k[i0]    = f2bf(x1*c - x2*si);
    k[i0+64] = f2bf(x2*c + x1*si);
  }
}

// ---------------- V transpose per (b,kvh): [1024 x 128] (stride vstr) -> vt [128 x 1024] ----------------
__global__ __launch_bounds__(256) void vtrans(const u16* __restrict__ v, u16* __restrict__ vt, int vstr) {
  __shared__ u16 tile[32][33];
  int bh = blockIdx.z; int b = bh >> 3, kvh = bh & 7;
  int d0 = blockIdx.x << 5, s0 = blockIdx.y << 5;
  int tx = threadIdx.x, ty = threadIdx.y;
  for (int r = ty; r < 32; r += 8)
    tile[r][tx] = v[(size_t)(b*1024 + s0 + r)*vstr + kvh*128 + d0 + tx];
  __syncthreads();
  for (int r = ty; r < 32; r += 8)
    vt[(size_t)((b*8 + kvh)*128 + d0 + r)*1024 + s0 + tx] = tile[tx][r];
}

// ---------------- 128-tile GEMM (merged K+V projection) ----------------
template<int EPI>
__global__ __launch_bounds__(256, 2) void gemm_bt(
    const u16* __restrict__ A, const u16* __restrict__ Bt,
    void* __restrict__ Cv, const float* __restrict__ resid,
    const u16* __restrict__ gate, int M, int N, int K) {
  __shared__ u16 As[128*64];
  __shared__ u16 Bs[128*64];
  int nwg = gridDim.x;
  int bid = (int)blockIdx.x;
  int cpx = nwg >> 3;
  int swz = (bid & 7) * cpx + (bid >> 3);
  int mt = M >> 7;
  int m0 = (swz % mt) << 7;
  int n0 = (swz / mt) << 7;
  int tid = threadIdx.x;
  int lane = tid & 63, wave = tid >> 6;
  int wm = wave >> 1, wn = wave & 1;

  f32x4 acc[4][4];
  f32x4 zero = {0.f, 0.f, 0.f, 0.f};
  #pragma unroll
  for (int i = 0; i < 4; i++)
    #pragma unroll
    for (int j = 0; j < 4; j++) acc[i][j] = zero;

  int arow[4], acolb[4];
  #pragma unroll
  for (int i = 0; i < 4; i++) {
    int c = i*256 + tid;
    arow[i]  = c >> 3;
    acolb[i] = ((c & 7) * 16) ^ ((arow[i] & 7) << 4);
  }

  int nsteps = K >> 6;
  for (int t = 0; t < nsteps; t++) {
    int k0 = t << 6;
    #pragma unroll
    for (int i = 0; i < 4; i++) {
      async16(As + i*2048 + wave*512, A  + (size_t)(m0 + arow[i])*K + k0 + (acolb[i] >> 1));
      async16(Bs + i*2048 + wave*512, Bt + (size_t)(n0 + arow[i])*K + k0 + (acolb[i] >> 1));
    }
    __syncthreads();
    #pragma unroll
    for (int ks = 0; ks < 2; ks++) {
      bf16x8 af[4], bfr[4];
      int c2 = (ks*32 + (lane >> 4)*8) * 2;
      #pragma unroll
      for (int mf = 0; mf < 4; mf++) {
        int r = wm*64 + mf*16 + (lane & 15);
        af[mf] = *(const bf16x8*)(As + r*64 + ((c2 ^ ((r & 7) << 4)) >> 1));
      }
      #pragma unroll
      for (int nf = 0; nf < 4; nf++) {
        int r = wn*64 + nf*16 + (lane & 15);
        bfr[nf] = *(const bf16x8*)(Bs + r*64 + ((c2 ^ ((r & 7) << 4)) >> 1));
      }
      #pragma unroll
      for (int mf = 0; mf < 4; mf++)
        #pragma unroll
        for (int nf = 0; nf < 4; nf++)
          acc[mf][nf] = __builtin_amdgcn_mfma_f32_16x16x32_bf16(af[mf], bfr[nf], acc[mf][nf], 0, 0, 0);
    }
    __syncthreads();
  }

  #pragma unroll
  for (int mf = 0; mf < 4; mf++)
    #pragma unroll
    for (int nf = 0; nf < 4; nf++)
      #pragma unroll
      for (int j = 0; j < 4; j++) {
        int rr = m0 + wm*64 + mf*16 + (lane >> 4)*4 + j;
        int cc = n0 + wn*64 + nf*16 + (lane & 15);
        size_t idx = (size_t)rr * N + cc;
        float v = acc[mf][nf][j];
        if constexpr (EPI == 0) {
          ((u16*)Cv)[idx] = f2bf(v);
        } else if constexpr (EPI == 1) {
          ((float*)Cv)[idx] = v + resid[idx];
        } else {
          float g = bf2f(gate[idx]);
          float sg = g / (1.f + __expf(-g));
          ((u16*)Cv)[idx] = f2bf(sg * v);
        }
      }
}

// ---------------- 256x256 GEMM: SINGLE-buffer, 64 KiB LDS; HW-determined 2 blocks/CU ----------
// launch_bounds(512,2): compiler targets >=2 waves/EU (1 block/CU) -> VGPR <= 256 (emits 128, as
// r11). At 128 VGPR + 64 KiB LDS, HARDWARE can co-schedule 2 blocks/CU (16 waves/CU): one block's
// LDS-read phase overlaps the other's MFMA phase. (r12's (512,4) forced VGPR=64 -> spill disaster.)
// All operands read to regs BEFORE MFMA; after lgkm drain the buffer is dead -> stage(t+1) flight
// hides under the 64 register-only MFMAs. Race-free: only full-drain __syncthreads, 2 per K-tile.
// EPI: 0 = bf16 C; 1 = fp32 C + resid; 3 = interleaved gate/up -> act = silu(g)*u, [M][11008] bf16.
#define MFMAQ(qm, qn, AF, BQ) do { \
  __builtin_amdgcn_s_setprio(1); \
  _Pragma("unroll") for (int mf_ = 0; mf_ < 4; mf_++) \
  _Pragma("unroll") for (int nf_ = 0; nf_ < 2; nf_++) \
  _Pragma("unroll") for (int ks_ = 0; ks_ < 2; ks_++) \
    acc[(qm)*4+mf_][(qn)*2+nf_] = __builtin_amdgcn_mfma_f32_16x16x32_bf16( \
        AF[mf_][ks_], BQ[nf_][ks_], acc[(qm)*4+mf_][(qn)*2+nf_], 0, 0, 0); \
  __builtin_amdgcn_s_setprio(0); } while (0)

template<int KC, int EPI>
__global__ __launch_bounds__(512, 2) void gemm256(
    const u16* __restrict__ A, const u16* __restrict__ Bt,
    void* __restrict__ Cv, const float* __restrict__ resid,
    int M, int N, int G,
    const float* __restrict__ cvin, u16* __restrict__ cvout, int cvK, int cvN, int cvTiles, int cvMode) {
  extern __shared__ u16 lds[];                  // single buffer: A 32KB | B 32KB = 64 KiB
  int bid = (int)blockIdx.x;
  int tid = threadIdx.x;

  if (bid >= G) {                               // hosted conv blocks (2 x 16.9KB tiles <= 64KB)
    int cb = bid - G, CB = (int)gridDim.x - G;
    int h = tid >> 8, t = tid & 255;
    float (*tl)[65] = (float(*)[65])((char*)lds + h*16896);
    int pairs = cvTiles >> 1;
    for (int p = cb; p < pairs; p += CB)
      conv_one(cvin, cvout, cvK, cvN, 2*p + h, t, tl, cvMode);
    return;
  }

  int cpx = G >> 3;
  int swz = (bid & 7) * cpx + (bid >> 3);       // XCD swizzle (T1); G % 8 == 0
  int mt = M >> 8;
  int m0 = (swz % mt) << 8;
  int n0 = (swz / mt) << 8;
  int lane = tid & 63, wave = tid >> 6;
  int wm = wave >> 2, wn = wave & 3;

  f32x4 acc[8][4];
  f32x4 zero = {0.f, 0.f, 0.f, 0.f};
  #pragma unroll
  for (int i = 0; i < 8; i++)
    #pragma unroll
    for (int j = 0; j < 4; j++) acc[i][j] = zero;

  // staging addresses (global pre-swizzled, LDS linear — rule #21)
  int sCol = ((lane & 7) ^ (lane >> 3)) << 3;
  int aRow = (wave >> 2)*128 + (wave & 3)*16 + (lane >> 3);
  int bRow = (wave >> 1)*64  + (wave & 1)*16 + (lane >> 3);
  const u16* gA = A  + (size_t)(m0 + aRow) * KC + sCol;
  const u16* gB = Bt + (size_t)(n0 + bRow) * KC + sCol;
  constexpr size_t K8 = (size_t)8 * KC, K32 = (size_t)32 * KC, K64 = (size_t)64 * KC;

  // fragment read offsets: stored chunk = logical ^ (row&7)
  int rA = lane & 15;
  int acol0 = (((lane >> 4)    ) ^ (rA & 7)) << 3;
  int acol1 = (((lane >> 4) + 4) ^ (rA & 7)) << 3;

  bf16x8 afA[4][2], afB[4][2], b0[2][2], b1[2][2];

  auto stageAq = [&](int qm, int k0) {
    u16* d = lds + qm*8192 + wave*1024;
    const u16* s = gA + (size_t)qm*K64 + k0;
    async16(d, s); async16(d + 512, s + K8);
  };
  auto stageBq = [&](int qn, int k0) {
    u16* d = lds + 16384 + qn*8192 + wave*1024;
    const u16* s = gB + (size_t)qn*K32 + k0;
    async16(d, s); async16(d + 512, s + K8);
  };
  auto stageAll = [&](int k0) {
    stageAq(0, k0); stageAq(1, k0);
    stageBq(0, k0); stageBq(1, k0);
  };
  auto loadAq = [&](int qm, bf16x8 (&af)[4][2]) {
    const u16* base = lds + qm*8192 + wm*4096 + rA*64;
    #pragma unroll
    for (int mf = 0; mf < 4; mf++) {
      af[mf][0] = *(const bf16x8*)(base + mf*1024 + acol0);
      af[mf][1] = *(const bf16x8*)(base + mf*1024 + acol1);
    }
  };
  auto loadBq = [&](int qn, bf16x8 (&bq)[2][2]) {
    const u16* base = lds + 16384 + qn*8192 + wn*2048 + rA*64;
    #pragma unroll
    for (int nf = 0; nf < 2; nf++) {
      bq[nf][0] = *(const bf16x8*)(base + nf*1024 + acol0);
      bq[nf][1] = *(const bf16x8*)(base + nf*1024 + acol1);
    }
  };

  constexpr int nt = KC >> 6;
  stageAll(0);
  __syncthreads();                              // tile 0 landed (full drain)
  #pragma unroll 1
  for (int t = 0; t < nt; t++) {
    // 1) pull ALL operands into registers (24 x ds_read_b128 per wave)
    loadAq(0, afA); loadBq(0, b0); loadBq(1, b1); loadAq(1, afB);
    __syncthreads();                            // lgkm drained: buffer dead, all waves done reading
    // 2) stage next tile into the (now-dead) buffer; flight hides under the MFMAs below
    if (t + 1 < nt) stageAll((t + 1) << 6);
    // 3) 64 register-only MFMAs
    MFMAQ(0, 0, afA, b0);
    MFMAQ(0, 1, afA, b1);
    MFMAQ(1, 0, afB, b0);
    MFMAQ(1, 1, afB, b1);
    __syncthreads();                            // vm drained: next tile landed for everyone
  }

  if constexpr (EPI == 3) {
    // acc[mf][nf] (nf=0,1) = gate, acc[mf][nf+2] = up, SAME output column (in-thread pairing)
    int colb = (n0 >> 1) + wn*32 + (lane & 15);
    #pragma unroll
    for (int mf = 0; mf < 8; mf++)
      #pragma unroll
      for (int nf = 0; nf < 2; nf++)
        #pragma unroll
        for (int j = 0; j < 4; j++) {
          int rr = m0 + wm*128 + mf*16 + (lane >> 4)*4 + j;
          float g = acc[mf][nf][j];
          float u = acc[mf][nf+2][j];
          float sg = g / (1.f + __expf(-g));
          ((u16*)Cv)[(size_t)rr * 11008 + colb + nf*16] = f2bf(sg * u);
        }
  } else {
    #pragma unroll
    for (int mf = 0; mf < 8; mf++)
      #pragma unroll
      for (int nf = 0; nf < 4; nf++)
        #pragma unroll
        for (int j = 0; j < 4; j++) {
          int rr = m0 + wm*128 + mf*16 + (lane >> 4)*4 + j;
          int cc = n0 + wn*64 + nf*16 + (lane & 15);
          size_t idx = (size_t)rr * N + cc;
          float v = acc[mf][nf][j];
          if constexpr (EPI == 0) {
            ((u16*)Cv)[idx] = f2bf(v);
          } else if constexpr (EPI == 1) {
            ((float*)Cv)[idx] = v + resid[idx];
          }
        }
  }
}

// ---------------- Flash attention, causal, GQA 4:1 (+ hosted weight-conversion blocks) ----------------
__global__ __launch_bounds__(256, 4) void attn_kernel(
    const u16* __restrict__ q, const u16* __restrict__ k,
    const u16* __restrict__ vt, u16* __restrict__ out,
    CJob j0, CJob j1, CJob j2, int kstr) {
  __shared__ __align__(16) u16 shm[20480];      // 40 KB: Ks 16K | Vs 16K | Ps 8K
  u16* Ks = shm;
  u16* Vs = shm + 8192;
  u16* Ps = shm + 16384;
  int bid = blockIdx.x;

  if (bid >= 2048) {                            // hosted conv blocks
    int cb = bid - 2048, CB = (int)gridDim.x - 2048;
    float (*tl)[65] = (float(*)[65])shm;
    int ntot = j0.ntiles + j1.ntiles + j2.ntiles;
    for (int g = cb; g < ntot; g += CB) {
      CJob* jp; int tile;
      if (g < j0.ntiles)                  { jp = &j0; tile = g; }
      else if (g < j0.ntiles + j1.ntiles) { jp = &j1; tile = g - j0.ntiles; }
      else                                { jp = &j2; tile = g - j0.ntiles - j1.ntiles; }
      conv_one(jp->in, jp->out, jp->K, jp->N, tile, threadIdx.x, tl, jp->mode);
    }
    return;
  }

  int qt = bid & 15;
  int h  = (bid >> 4) & 31;
  int b  = bid >> 9;
  int kvh = h >> 2;
  int tid = threadIdx.x, lane = tid & 63, wave = tid >> 6;
  int q0 = qt << 6;

  bf16x8 qf[4];
  {
    const u16* qb_ = q + (size_t)(b*1024 + q0 + wave*16 + (lane & 15))*4096 + h*128 + (lane >> 4)*8;
    #pragma unroll
    for (int ks = 0; ks < 4; ks++) qf[ks] = *(const bf16x8*)(qb_ + ks*32);
  }
  f32x4 o[8];
  f32x4 zero = {0.f,0.f,0.f,0.f};
  #pragma unroll
  for (int i = 0; i < 8; i++) o[i] = zero;
  float m[4] = {-1e30f,-1e30f,-1e30f,-1e30f};
  float l[4] = {0.f,0.f,0.f,0.f};

  int kr[4], kc[4], vr[4], vc[4];
  #pragma unroll
  for (int i = 0; i < 4; i++) {
    int c = i*256 + tid;
    kr[i] = c >> 4; kc[i] = ((c & 15)*16) ^ ((kr[i] & 7) << 4);
    vr[i] = c >> 3; vc[i] = ((c & 7)*16)  ^ ((vr[i] & 7) << 4);
  }

  for (int t = 0; t <= qt; t++) {
    int kv0 = t << 6;
    #pragma unroll
    for (int i = 0; i < 4; i++) {
      async16(Ks + i*2048 + wave*512, k  + (size_t)(b*1024 + kv0 + kr[i])*kstr + kvh*128 + (kc[i] >> 1));
      async16(Vs + i*2048 + wave*512, vt + (size_t)((b*8 + kvh)*128 + vr[i])*1024 + kv0 + (vc[i] >> 1));
    }
    __syncthreads();

    f32x4 s[4];
    #pragma unroll
    for (int nf = 0; nf < 4; nf++) {
      s[nf] = zero;
      #pragma unroll
      for (int ks = 0; ks < 4; ks++) {
        int r = nf*16 + (lane & 15);
        int c2 = (ks*32 + (lane >> 4)*8)*2;
        bf16x8 kf = *(const bf16x8*)(Ks + r*128 + ((c2 ^ ((r & 7) << 4)) >> 1));
        s[nf] = __builtin_amdgcn_mfma_f32_16x16x32_bf16(qf[ks], kf, s[nf], 0, 0, 0);
      }
    }
    if (t == qt) {
      #pragma unroll
      for (int nf = 0; nf < 4; nf++)
        #pragma unroll
        for (int j = 0; j < 4; j++) {
          int cc = nf*16 + (lane & 15);
          int rr = wave*16 + (lane >> 4)*4 + j;
          if (cc > rr) s[nf][j] = -1e30f;
        }
    }
    #pragma unroll
    for (int j = 0; j < 4; j++) {
      float mx = fmaxf(fmaxf(s[0][j], s[1][j]), fmaxf(s[2][j], s[3][j]));
      #pragma unroll
      for (int d = 1; d < 16; d <<= 1) mx = fmaxf(mx, __shfl_xor(mx, d, 64));
      float mn = fmaxf(m[j], mx);
      float f = __expf(m[j] - mn);
      m[j] = mn;
      float ssum = 0.f;
      #pragma unroll
      for (int nf = 0; nf < 4; nf++) {
        float p = __expf(s[nf][j] - mn);
        s[nf][j] = p; ssum += p;
      }
      #pragma unroll
      for (int d = 1; d < 16; d <<= 1) ssum += __shfl_xor(ssum, d, 64);
      l[j] = l[j]*f + ssum;
      #pragma unroll
      for (int nf = 0; nf < 8; nf++) o[nf][j] *= f;
    }
    #pragma unroll
    for (int nf = 0; nf < 4; nf++)
      #pragma unroll
      for (int j = 0; j < 4; j++) {
        int rr = (lane >> 4)*4 + j;
        int cb2 = ((nf*16 + (lane & 15))*2) ^ ((rr & 7) << 4);
        Ps[wave*1024 + rr*64 + (cb2 >> 1)] = f2bf(s[nf][j]);
      }
    #pragma unroll
    for (int ks2 = 0; ks2 < 2; ks2++) {
      int mr = lane & 15;
      int c2 = (ks2*32 + (lane >> 4)*8)*2;
      bf16x8 pa = *(const bf16x8*)(Ps + wave*1024 + mr*64 + ((c2 ^ ((mr & 7) << 4)) >> 1));
      #pragma unroll
      for (int nf = 0; nf < 8; nf++) {
        int d = nf*16 + (lane & 15);
        bf16x8 vf = *(const bf16x8*)(Vs + d*64 + ((c2 ^ ((d & 7) << 4)) >> 1));
        o[nf] = __builtin_amdgcn_mfma_f32_16x16x32_bf16(pa, vf, o[nf], 0, 0, 0);
      }
    }
    __syncthreads();
  }

  float inv[4];
  #pragma unroll
  for (int j = 0; j < 4; j++) inv[j] = 1.f / l[j];
  u16* ob = out + (size_t)(b*1024 + q0 + wave*16)*4096 + h*128;
  #pragma unroll
  for (int nf = 0; nf < 8; nf++)
    #pragma unroll
    for (int j = 0; j < 4; j++) {
      int rr = (lane >> 4)*4 + j;
      int cc = nf*16 + (lane & 15);
      ob[(size_t)rr*4096 + cc] = f2bf(o[nf][j] * inv[j]);
    }
}

// ---------------- driver ----------------
extern "C" void kernel_launch(void* const* d_in, const int* in_sizes, int n_in,
                              void* d_out, int out_size, void* d_ws, size_t ws_size,
                              hipStream_t stream) {
  (void)in_sizes; (void)n_in; (void)out_size;
  const float* hidden = (const float*)d_in[0];
  const float* Wq  = (const float*)d_in[3];
  const float* Wk  = (const float*)d_in[4];
  const float* Wv  = (const float*)d_in[5];
  const float* Wo  = (const float*)d_in[6];
  const float* ln1 = (const float*)d_in[7];
  const float* ln2 = (const float*)d_in[8];
  const float* Wg  = (const float*)d_in[9];
  const float* Wu  = (const float*)d_in[10];
  const float* Wd  = (const float*)d_in[11];
  float* out = (float*)d_out;

  hipFuncSetAttribute((const void*)gemm256<4096,0>,  hipFuncAttributeMaxDynamicSharedMemorySize, 65536);
  hipFuncSetAttribute((const void*)gemm256<4096,1>,  hipFuncAttributeMaxDynamicSharedMemorySize, 65536);
  hipFuncSetAttribute((const void*)gemm256<4096,3>,  hipFuncAttributeMaxDynamicSharedMemorySize, 65536);
  hipFuncSetAttribute((const void*)gemm256<11008,1>, hipFuncAttributeMaxDynamicSharedMemorySize, 65536);

  char* ws = (char*)d_ws;
  size_t off = 0;
  auto alloc = [&](size_t b) { char* p = ws + off; off += (b + 4095) & ~(size_t)4095; return p; };

  u16*  wqkvT = (u16*)alloc(50331648);   // [6144][4096] bf16: wq | wk | wv
  u16*  woT   = (u16*)alloc(33554432);
  (void)alloc(8388608);                  // pad: lets wdT (86 MiB) alias wqkvT+woT+pad
  u16*  wguT  = (u16*)alloc(180355072);  // [22016][4096] interleaved gate/up (64-row = 32g+32u)
  u16*  h1    = (u16*)alloc(33554432);
  u16*  qb    = (u16*)alloc(33554432);
  u16*  kvb   = (u16*)alloc(16777216);   // [4096 tok][2048]: k | v
  u16*  vtb   = (u16*)alloc(8388608);
  float* hmid = (float*)alloc(67108864);
  u16*  gb    = (u16*)alloc(90177536);   // act [4096][11008] bf16
  if (off > ws_size) return;             // ws too small -> fail visibly

  u16* wqT  = wqkvT;
  u16* wkvT = wqkvT + 16777216;
  u16* wkT  = wkvT;
  u16* wvT  = wkvT + 4194304;
  u16* wdT  = wqkvT;                     // aliases wqkvT+woT+pad, both dead by gateup time
  CJob Jq{Wq, wqT, 4096, 4096, 4096, 0}, Jk{Wk, wkT, 4096, 1024, 1024, 0}, Jv{Wv, wvT, 4096, 1024, 1024, 0};
  CJob Jo{Wo, woT, 4096, 4096, 4096, 0};
  CJob Jg{Wg, wguT, 4096, 11008, 11008, 1}, Ju{Wu, wguT, 4096, 11008, 11008, 2};

  dim3 blk(256);
  conv3<<<2048, blk, 0, stream>>>(Jq, Jk, Jv);
  rmsnorm_kernel<<<4096, blk, 0, stream>>>(hidden, ln1, h1);
  gemm256<4096,0><<<256, 512, 65536, stream>>>(h1, wqT, qb, nullptr, 4096, 4096, 256,
                                               nullptr, nullptr, 0, 0, 0, 0);
  gemm_bt<0><<<512, blk, 0, stream>>>(h1, wkvT, kvb, nullptr, nullptr, 4096, 2048, 4096);
  rope_kernel<<<4096, blk, 0, stream>>>(qb, kvb, 2048);
  vtrans<<<dim3(4, 32, 32), dim3(32, 8), 0, stream>>>(kvb + 1024, vtb, 2048);
  // attention + hosted conversions of Wo (plain), Wg/Wu (interleaved into wguT)
  attn_kernel<<<2048 + 1024, blk, 0, stream>>>(qb, kvb, vtb, h1, Jo, Jg, Ju, 2048);
  gemm256<4096,1><<<256, 512, 65536, stream>>>(h1, woT, hmid, hidden, 4096, 4096, 256,
                                               nullptr, nullptr, 0, 0, 0, 0);
  rmsnorm_kernel<<<4096, blk, 0, stream>>>(hmid, ln2, qb);
  // merged gate+up GEMM (N-rows 22016 -> act [4096][11008]) + hosted Wd conversion
  gemm256<4096,3><<<1376 + 344, 512, 65536, stream>>>(qb, wguT, gb, nullptr, 4096, 11008, 1376,
                                                      Wd, wdT, 11008, 4096, 11008, 0);
  gemm256<11008,1><<<256, 512, 65536, stream>>>(gb, wdT, out, hmid, 4096, 4096, 256,
                                                nullptr, nullptr, 0, 0, 0, 0);
}

// Round 14
// 1618.035 us; speedup vs baseline: 9.0867x; 1.0743x over previous
//
#include <hip/hip_runtime.h>

#define DEVINL __device__ __forceinline__

typedef unsigned short u16;
typedef __attribute__((ext_vector_type(8))) short bf16x8;   // 8 bf16 = 4 VGPRs (MFMA A/B frag)
typedef __attribute__((ext_vector_type(4))) float f32x4;     // MFMA C/D frag
typedef __attribute__((ext_vector_type(4))) unsigned short u16x4;

// B=4, S=1024, HID=4096, NH=32, NKV=8, HD=128, FF=11008

DEVINL float bf2f(u16 u) { union { unsigned i; float f; } x; x.i = ((unsigned)u) << 16; return x.f; }
DEVINL u16 f2bf(float f) {                       // round-to-nearest-even
  union { float f; unsigned i; } x; x.f = f;
  unsigned r = x.i + 0x7fffu + ((x.i >> 16) & 1u);
  return (u16)(r >> 16);
}

DEVINL void async16(u16* lds, const u16* g) {
  __builtin_amdgcn_global_load_lds((const __attribute__((address_space(1))) unsigned*)g,
                                   (__attribute__((address_space(3))) unsigned*)lds, 16, 0, 0);
}

struct CJob { const float* in; u16* out; int K, N, ntiles; int mode; };
// mode 0: out row = col index n (plain transpose)
// mode 1: gate-interleave: row = (n>>5)*64 + (n&31)
// mode 2: up-interleave:   row = (n>>5)*64 + 32 + (n&31)

// one 64x64 convert+transpose tile; 256 participating threads; 2 block-wide syncs
DEVINL void conv_one(const float* __restrict__ in, u16* __restrict__ out,
                     int K, int N, int tile, int t, float (*tl)[65], int mode) {
  int tn = N >> 6;
  int kt = tile / tn;
  int k0 = kt << 6, n0 = (tile - kt*tn) << 6;
  int r = t >> 4, c4 = (t & 15) << 2;
  #pragma unroll
  for (int it = 0; it < 4; it++) {
    int row = r + it*16;
    f32x4 v = *(const f32x4*)(in + (size_t)(k0 + row)*N + n0 + c4);
    tl[row][c4+0] = v[0]; tl[row][c4+1] = v[1];
    tl[row][c4+2] = v[2]; tl[row][c4+3] = v[3];
  }
  __syncthreads();
  #pragma unroll
  for (int it = 0; it < 4; it++) {
    int nrow = r + it*16;
    u16x4 ov;
    #pragma unroll
    for (int e = 0; e < 4; e++) ov[e] = f2bf(tl[c4+e][nrow]);
    int orow = n0 + nrow;
    if (mode == 1)      orow = ((orow >> 5) << 6) + (orow & 31);
    else if (mode == 2) orow = ((orow >> 5) << 6) + 32 + (orow & 31);
    *(u16x4*)(out + (size_t)orow*K + k0 + c4) = ov;
  }
  __syncthreads();
}

// ---------------- standalone conv (QKV), grid-stride over 3 jobs ----------------
__global__ __launch_bounds__(256) void conv3(CJob j0, CJob j1, CJob j2) {
  __shared__ float tl[64][65];
  int ntot = j0.ntiles + j1.ntiles + j2.ntiles;
  for (int g = blockIdx.x; g < ntot; g += gridDim.x) {
    CJob* jp;
    int tile;
    if (g < j0.ntiles)                 { jp = &j0; tile = g; }
    else if (g < j0.ntiles + j1.ntiles){ jp = &j1; tile = g - j0.ntiles; }
    else                               { jp = &j2; tile = g - j0.ntiles - j1.ntiles; }
    conv_one(jp->in, jp->out, jp->K, jp->N, tile, threadIdx.x, tl, jp->mode);
  }
}

// ---------------- RMSNorm: fp32 in [4096 rows x 4096] -> bf16 out ----------------
__global__ __launch_bounds__(256) void rmsnorm_kernel(const float* __restrict__ x,
                                                      const float* __restrict__ w,
                                                      u16* __restrict__ out) {
  int row = blockIdx.x, t = threadIdx.x;
  const float* xr = x + (size_t)row * 4096;
  f32x4 v[4];
  float ss = 0.f;
  #pragma unroll
  for (int i = 0; i < 4; i++) {
    v[i] = *(const f32x4*)(xr + (t + 256*i)*4);
    ss += v[i][0]*v[i][0] + v[i][1]*v[i][1] + v[i][2]*v[i][2] + v[i][3]*v[i][3];
  }
  #pragma unroll
  for (int d = 1; d < 64; d <<= 1) ss += __shfl_xor(ss, d, 64);
  __shared__ float ps[4];
  if ((t & 63) == 0) ps[t >> 6] = ss;
  __syncthreads();
  float scale = rsqrtf((ps[0]+ps[1]+ps[2]+ps[3]) * (1.f/4096.f) + 1e-6f);
  #pragma unroll
  for (int i = 0; i < 4; i++) {
    f32x4 wv = *(const f32x4*)(w + (t + 256*i)*4);
    u16x4 o;
    #pragma unroll
    for (int e = 0; e < 4; e++) o[e] = f2bf(v[i][e] * scale * wv[e]);
    *(u16x4*)(out + (size_t)row*4096 + (t + 256*i)*4) = o;
  }
}

// ---------------- RoPE in-place on q [tok,4096] & k [tok, kstr]; q gets 1/sqrt(HD) ----------------
__global__ __launch_bounds__(256) void rope_kernel(u16* __restrict__ q, u16* __restrict__ k, int kstr) {
  int tok = blockIdx.x;
  int s = tok & 1023;
  __shared__ float cs[64], sn[64];
  int t = threadIdx.x;
  if (t < 64) {
    float inv = __expf(-(float)t * 0.14391156934f);
    float ang = (float)s * inv;
    cs[t] = cosf(ang); sn[t] = sinf(ang);
  }
  __syncthreads();
  const float qscale = 0.08838834764831845f;
  size_t qbase = (size_t)tok * 4096;
  #pragma unroll
  for (int it = 0; it < 8; it++) {
    int item = t + it*256; int h = item >> 6, j = item & 63;
    size_t i0 = qbase + h*128 + j;
    float x1 = bf2f(q[i0]), x2 = bf2f(q[i0+64]);
    float c = cs[j], si = sn[j];
    q[i0]    = f2bf((x1*c - x2*si) * qscale);
    q[i0+64] = f2bf((x2*c + x1*si) * qscale);
  }
  size_t kbase = (size_t)tok * kstr;
  #pragma unroll
  for (int it = 0; it < 2; it++) {
    int item = t + it*256; int h = item >> 6, j = item & 63;
    size_t i0 = kbase + h*128 + j;
    float x1 = bf2f(k[i0]), x2 = bf2f(k[i0+64]);
    float c = cs[j], si = sn[j];
    k[i0]    = f2bf(x1*c - x2*si);
    k[i0+64] = f2bf(x2*c + x1*si);
  }
}

// ---------------- V transpose per (b,kvh): [1024 x 128] (stride vstr) -> vt [128 x 1024] ----------------
__global__ __launch_bounds__(256) void vtrans(const u16* __restrict__ v, u16* __restrict__ vt, int vstr) {
  __shared__ u16 tile[32][33];
  int bh = blockIdx.z; int b = bh >> 3, kvh = bh & 7;
  int d0 = blockIdx.x << 5, s0 = blockIdx.y << 5;
  int tx = threadIdx.x, ty = threadIdx.y;
  for (int r = ty; r < 32; r += 8)
    tile[r][tx] = v[(size_t)(b*1024 + s0 + r)*vstr + kvh*128 + d0 + tx];
  __syncthreads();
  for (int r = ty; r < 32; r += 8)
    vt[(size_t)((b*8 + kvh)*128 + d0 + r)*1024 + s0 + tx] = tile[tx][r];
}

// ---------------- 128-tile GEMM (merged K+V projection) ----------------
template<int EPI>
__global__ __launch_bounds__(256, 2) void gemm_bt(
    const u16* __restrict__ A, const u16* __restrict__ Bt,
    void* __restrict__ Cv, const float* __restrict__ resid,
    const u16* __restrict__ gate, int M, int N, int K) {
  __shared__ u16 As[128*64];
  __shared__ u16 Bs[128*64];
  int nwg = gridDim.x;
  int bid = (int)blockIdx.x;
  int cpx = nwg >> 3;
  int swz = (bid & 7) * cpx + (bid >> 3);
  int mt = M >> 7;
  int m0 = (swz % mt) << 7;
  int n0 = (swz / mt) << 7;
  int tid = threadIdx.x;
  int lane = tid & 63, wave = tid >> 6;
  int wm = wave >> 1, wn = wave & 1;

  f32x4 acc[4][4];
  f32x4 zero = {0.f, 0.f, 0.f, 0.f};
  #pragma unroll
  for (int i = 0; i < 4; i++)
    #pragma unroll
    for (int j = 0; j < 4; j++) acc[i][j] = zero;

  int arow[4], acolb[4];
  #pragma unroll
  for (int i = 0; i < 4; i++) {
    int c = i*256 + tid;
    arow[i]  = c >> 3;
    acolb[i] = ((c & 7) * 16) ^ ((arow[i] & 7) << 4);
  }

  int nsteps = K >> 6;
  for (int t = 0; t < nsteps; t++) {
    int k0 = t << 6;
    #pragma unroll
    for (int i = 0; i < 4; i++) {
      async16(As + i*2048 + wave*512, A  + (size_t)(m0 + arow[i])*K + k0 + (acolb[i] >> 1));
      async16(Bs + i*2048 + wave*512, Bt + (size_t)(n0 + arow[i])*K + k0 + (acolb[i] >> 1));
    }
    __syncthreads();
    #pragma unroll
    for (int ks = 0; ks < 2; ks++) {
      bf16x8 af[4], bfr[4];
      int c2 = (ks*32 + (lane >> 4)*8) * 2;
      #pragma unroll
      for (int mf = 0; mf < 4; mf++) {
        int r = wm*64 + mf*16 + (lane & 15);
        af[mf] = *(const bf16x8*)(As + r*64 + ((c2 ^ ((r & 7) << 4)) >> 1));
      }
      #pragma unroll
      for (int nf = 0; nf < 4; nf++) {
        int r = wn*64 + nf*16 + (lane & 15);
        bfr[nf] = *(const bf16x8*)(Bs + r*64 + ((c2 ^ ((r & 7) << 4)) >> 1));
      }
      #pragma unroll
      for (int mf = 0; mf < 4; mf++)
        #pragma unroll
        for (int nf = 0; nf < 4; nf++)
          acc[mf][nf] = __builtin_amdgcn_mfma_f32_16x16x32_bf16(af[mf], bfr[nf], acc[mf][nf], 0, 0, 0);
    }
    __syncthreads();
  }

  #pragma unroll
  for (int mf = 0; mf < 4; mf++)
    #pragma unroll
    for (int nf = 0; nf < 4; nf++)
      #pragma unroll
      for (int j = 0; j < 4; j++) {
        int rr = m0 + wm*64 + mf*16 + (lane >> 4)*4 + j;
        int cc = n0 + wn*64 + nf*16 + (lane & 15);
        size_t idx = (size_t)rr * N + cc;
        float v = acc[mf][nf][j];
        if constexpr (EPI == 0) {
          ((u16*)Cv)[idx] = f2bf(v);
        } else if constexpr (EPI == 1) {
          ((float*)Cv)[idx] = v + resid[idx];
        } else {
          float g = bf2f(gate[idx]);
          float sg = g / (1.f + __expf(-g));
          ((u16*)Cv)[idx] = f2bf(sg * v);
        }
      }
}

// ---------------- 256x256 GEMM: SAFE double-buffered schedule (full-drain __syncthreads) ----------
// Race-free by construction: one __syncthreads per K-tile; each is a full vmcnt(0)+lgkmcnt(0)
// drain + barrier (compiler-emitted), so every stage-write and every ds_read is globally complete
// before any buffer is reused. Stage of tile t+1 is issued BEFORE compute of tile t, so its HBM
// latency hides under ~2500 cy of ds_read+MFMA. Static buffer parity (2 tiles per iteration).
// EPI: 0 = bf16 C; 1 = fp32 C + resid; 3 = interleaved gate/up -> act = silu(g)*u, [M][11008] bf16.
#define MFMAQ(qm, qn, AF, BQ) do { \
  __builtin_amdgcn_s_setprio(1); \
  _Pragma("unroll") for (int mf_ = 0; mf_ < 4; mf_++) \
  _Pragma("unroll") for (int nf_ = 0; nf_ < 2; nf_++) \
  _Pragma("unroll") for (int ks_ = 0; ks_ < 2; ks_++) \
    acc[(qm)*4+mf_][(qn)*2+nf_] = __builtin_amdgcn_mfma_f32_16x16x32_bf16( \
        AF[mf_][ks_], BQ[nf_][ks_], acc[(qm)*4+mf_][(qn)*2+nf_], 0, 0, 0); \
  __builtin_amdgcn_s_setprio(0); } while (0)

template<int KC, int EPI>
__global__ __launch_bounds__(512, 2) void gemm256(
    const u16* __restrict__ A, const u16* __restrict__ Bt,
    void* __restrict__ Cv, const float* __restrict__ resid,
    int M, int N, int G,
    const float* __restrict__ cvin, u16* __restrict__ cvout, int cvK, int cvN, int cvTiles, int cvMode) {
  extern __shared__ u16 lds[];
  int bid = (int)blockIdx.x;
  int tid = threadIdx.x;

  if (bid >= G) {                               // hosted conv blocks
    int cb = bid - G, CB = (int)gridDim.x - G;
    int h = tid >> 8, t = tid & 255;
    float (*tl)[65] = (float(*)[65])((char*)lds + h*16896);
    int pairs = cvTiles >> 1;
    for (int p = cb; p < pairs; p += CB)
      conv_one(cvin, cvout, cvK, cvN, 2*p + h, t, tl, cvMode);
    return;
  }

  int cpx = G >> 3;
  int swz = (bid & 7) * cpx + (bid >> 3);       // XCD swizzle (T1); G % 8 == 0
  int mt = M >> 8;
  int m0 = (swz % mt) << 8;
  int n0 = (swz / mt) << 8;
  int lane = tid & 63, wave = tid >> 6;
  int wm = wave >> 2, wn = wave & 3;

  f32x4 acc[8][4];
  f32x4 zero = {0.f, 0.f, 0.f, 0.f};
  #pragma unroll
  for (int i = 0; i < 8; i++)
    #pragma unroll
    for (int j = 0; j < 4; j++) acc[i][j] = zero;

  // staging addresses (global pre-swizzled, LDS linear — rule #21)
  int sCol = ((lane & 7) ^ (lane >> 3)) << 3;
  int aRow = (wave >> 2)*128 + (wave & 3)*16 + (lane >> 3);
  int bRow = (wave >> 1)*64  + (wave & 1)*16 + (lane >> 3);
  const u16* gA = A  + (size_t)(m0 + aRow) * KC + sCol;
  const u16* gB = Bt + (size_t)(n0 + bRow) * KC + sCol;
  constexpr size_t K8 = (size_t)8 * KC, K32 = (size_t)32 * KC, K64 = (size_t)64 * KC;

  // fragment read offsets: stored chunk = logical ^ (row&7)
  int rA = lane & 15;
  int acol0 = (((lane >> 4)    ) ^ (rA & 7)) << 3;
  int acol1 = (((lane >> 4) + 4) ^ (rA & 7)) << 3;

  bf16x8 afA[4][2], afB[4][2], b0[2][2], b1[2][2];

  auto stageAq = [&](int buf, int qm, int k0) {
    u16* d = lds + buf*32768 + qm*8192 + wave*1024;
    const u16* s = gA + (size_t)qm*K64 + k0;
    async16(d, s); async16(d + 512, s + K8);
  };
  auto stageBq = [&](int buf, int qn, int k0) {
    u16* d = lds + buf*32768 + 16384 + qn*8192 + wave*1024;
    const u16* s = gB + (size_t)qn*K32 + k0;
    async16(d, s); async16(d + 512, s + K8);
  };
  auto stageAll = [&](int buf, int k0) {
    stageAq(buf, 0, k0); stageAq(buf, 1, k0);
    stageBq(buf, 0, k0); stageBq(buf, 1, k0);
  };
  auto loadAq = [&](int buf, int qm, bf16x8 (&af)[4][2]) {
    const u16* base = lds + buf*32768 + qm*8192 + wm*4096 + rA*64;
    #pragma unroll
    for (int mf = 0; mf < 4; mf++) {
      af[mf][0] = *(const bf16x8*)(base + mf*1024 + acol0);
      af[mf][1] = *(const bf16x8*)(base + mf*1024 + acol1);
    }
  };
  auto loadBq = [&](int buf, int qn, bf16x8 (&bq)[2][2]) {
    const u16* base = lds + buf*32768 + 16384 + qn*8192 + wn*2048 + rA*64;
    #pragma unroll
    for (int nf = 0; nf < 2; nf++) {
      bq[nf][0] = *(const bf16x8*)(base + nf*1024 + acol0);
      bq[nf][1] = *(const bf16x8*)(base + nf*1024 + acol1);
    }
  };
  auto computeTile = [&](int buf) {
    loadAq(buf, 0, afA); loadBq(buf, 0, b0); loadBq(buf, 1, b1); loadAq(buf, 1, afB);
    MFMAQ(0, 0, afA, b0);
    MFMAQ(0, 1, afA, b1);
    MFMAQ(1, 0, afB, b0);
    MFMAQ(1, 1, afB, b1);
  };

  constexpr int nt = KC >> 6;                   // even (64 or 172)
  stageAll(0, 0);
  __syncthreads();                              // tile 0 fully landed (full drain)
  #pragma unroll 1
  for (int it = 0; it < nt/2; it++) {
    int kc = it << 7;
    stageAll(1, kc + 64);                       // prefetch tile 2it+1 -> buf1
    computeTile(0);                             // compute tile 2it from buf0
    __syncthreads();                            // drain: buf1 landed, buf0 reads done
    if (kc + 128 < KC) stageAll(0, kc + 128);   // prefetch tile 2it+2 -> buf0
    computeTile(1);                             // compute tile 2it+1 from buf1
    __syncthreads();                            // drain: buf0 landed, buf1 reads done
  }

  if constexpr (EPI == 3) {
    // acc[mf][nf] (nf=0,1) = gate, acc[mf][nf+2] = up, SAME output column (in-thread pairing)
    int colb = (n0 >> 1) + wn*32 + (lane & 15);
    #pragma unroll
    for (int mf = 0; mf < 8; mf++)
      #pragma unroll
      for (int nf = 0; nf < 2; nf++)
        #pragma unroll
        for (int j = 0; j < 4; j++) {
          int rr = m0 + wm*128 + mf*16 + (lane >> 4)*4 + j;
          float g = acc[mf][nf][j];
          float u = acc[mf][nf+2][j];
          float sg = g / (1.f + __expf(-g));
          ((u16*)Cv)[(size_t)rr * 11008 + colb + nf*16] = f2bf(sg * u);
        }
  } else {
    #pragma unroll
    for (int mf = 0; mf < 8; mf++)
      #pragma unroll
      for (int nf = 0; nf < 4; nf++)
        #pragma unroll
        for (int j = 0; j < 4; j++) {
          int rr = m0 + wm*128 + mf*16 + (lane >> 4)*4 + j;
          int cc = n0 + wn*64 + nf*16 + (lane & 15);
          size_t idx = (size_t)rr * N + cc;
          float v = acc[mf][nf][j];
          if constexpr (EPI == 0) {
            ((u16*)Cv)[idx] = f2bf(v);
          } else if constexpr (EPI == 1) {
            ((float*)Cv)[idx] = v + resid[idx];
          }
        }
  }
}

// ---------------- Flash attention, causal, GQA 4:1 (+ hosted weight-conversion blocks) ----------------
__global__ __launch_bounds__(256, 4) void attn_kernel(
    const u16* __restrict__ q, const u16* __restrict__ k,
    const u16* __restrict__ vt, u16* __restrict__ out,
    CJob j0, CJob j1, CJob j2, int kstr) {
  __shared__ __align__(16) u16 shm[20480];      // 40 KB: Ks 16K | Vs 16K | Ps 8K
  u16* Ks = shm;
  u16* Vs = shm + 8192;
  u16* Ps = shm + 16384;
  int bid = blockIdx.x;

  if (bid >= 2048) {                            // hosted conv blocks
    int cb = bid - 2048, CB = (int)gridDim.x - 2048;
    float (*tl)[65] = (float(*)[65])shm;
    int ntot = j0.ntiles + j1.ntiles + j2.ntiles;
    for (int g = cb; g < ntot; g += CB) {
      CJob* jp; int tile;
      if (g < j0.ntiles)                  { jp = &j0; tile = g; }
      else if (g < j0.ntiles + j1.ntiles) { jp = &j1; tile = g - j0.ntiles; }
      else                                { jp = &j2; tile = g - j0.ntiles - j1.ntiles; }
      conv_one(jp->in, jp->out, jp->K, jp->N, tile, threadIdx.x, tl, jp->mode);
    }
    return;
  }

  int qt = bid & 15;
  int h  = (bid >> 4) & 31;
  int b  = bid >> 9;
  int kvh = h >> 2;
  int tid = threadIdx.x, lane = tid & 63, wave = tid >> 6;
  int q0 = qt << 6;

  bf16x8 qf[4];
  {
    const u16* qb_ = q + (size_t)(b*1024 + q0 + wave*16 + (lane & 15))*4096 + h*128 + (lane >> 4)*8;
    #pragma unroll
    for (int ks = 0; ks < 4; ks++) qf[ks] = *(const bf16x8*)(qb_ + ks*32);
  }
  f32x4 o[8];
  f32x4 zero = {0.f,0.f,0.f,0.f};
  #pragma unroll
  for (int i = 0; i < 8; i++) o[i] = zero;
  float m[4] = {-1e30f,-1e30f,-1e30f,-1e30f};
  float l[4] = {0.f,0.f,0.f,0.f};

  int kr[4], kc[4], vr[4], vc[4];
  #pragma unroll
  for (int i = 0; i < 4; i++) {
    int c = i*256 + tid;
    kr[i] = c >> 4; kc[i] = ((c & 15)*16) ^ ((kr[i] & 7) << 4);
    vr[i] = c >> 3; vc[i] = ((c & 7)*16)  ^ ((vr[i] & 7) << 4);
  }

  for (int t = 0; t <= qt; t++) {
    int kv0 = t << 6;
    #pragma unroll
    for (int i = 0; i < 4; i++) {
      async16(Ks + i*2048 + wave*512, k  + (size_t)(b*1024 + kv0 + kr[i])*kstr + kvh*128 + (kc[i] >> 1));
      async16(Vs + i*2048 + wave*512, vt + (size_t)((b*8 + kvh)*128 + vr[i])*1024 + kv0 + (vc[i] >> 1));
    }
    __syncthreads();

    f32x4 s[4];
    #pragma unroll
    for (int nf = 0; nf < 4; nf++) {
      s[nf] = zero;
      #pragma unroll
      for (int ks = 0; ks < 4; ks++) {
        int r = nf*16 + (lane & 15);
        int c2 = (ks*32 + (lane >> 4)*8)*2;
        bf16x8 kf = *(const bf16x8*)(Ks + r*128 + ((c2 ^ ((r & 7) << 4)) >> 1));
        s[nf] = __builtin_amdgcn_mfma_f32_16x16x32_bf16(qf[ks], kf, s[nf], 0, 0, 0);
      }
    }
    if (t == qt) {
      #pragma unroll
      for (int nf = 0; nf < 4; nf++)
        #pragma unroll
        for (int j = 0; j < 4; j++) {
          int cc = nf*16 + (lane & 15);
          int rr = wave*16 + (lane >> 4)*4 + j;
          if (cc > rr) s[nf][j] = -1e30f;
        }
    }
    #pragma unroll
    for (int j = 0; j < 4; j++) {
      float mx = fmaxf(fmaxf(s[0][j], s[1][j]), fmaxf(s[2][j], s[3][j]));
      #pragma unroll
      for (int d = 1; d < 16; d <<= 1) mx = fmaxf(mx, __shfl_xor(mx, d, 64));
      float mn = fmaxf(m[j], mx);
      float f = __expf(m[j] - mn);
      m[j] = mn;
      float ssum = 0.f;
      #pragma unroll
      for (int nf = 0; nf < 4; nf++) {
        float p = __expf(s[nf][j] - mn);
        s[nf][j] = p; ssum += p;
      }
      #pragma unroll
      for (int d = 1; d < 16; d <<= 1) ssum += __shfl_xor(ssum, d, 64);
      l[j] = l[j]*f + ssum;
      #pragma unroll
      for (int nf = 0; nf < 8; nf++) o[nf][j] *= f;
    }
    #pragma unroll
    for (int nf = 0; nf < 4; nf++)
      #pragma unroll
      for (int j = 0; j < 4; j++) {
        int rr = (lane >> 4)*4 + j;
        int cb2 = ((nf*16 + (lane & 15))*2) ^ ((rr & 7) << 4);
        Ps[wave*1024 + rr*64 + (cb2 >> 1)] = f2bf(s[nf][j]);
      }
    #pragma unroll
    for (int ks2 = 0; ks2 < 2; ks2++) {
      int mr = lane & 15;
      int c2 = (ks2*32 + (lane >> 4)*8)*2;
      bf16x8 pa = *(const bf16x8*)(Ps + wave*1024 + mr*64 + ((c2 ^ ((mr & 7) << 4)) >> 1));
      #pragma unroll
      for (int nf = 0; nf < 8; nf++) {
        int d = nf*16 + (lane & 15);
        bf16x8 vf = *(const bf16x8*)(Vs + d*64 + ((c2 ^ ((d & 7) << 4)) >> 1));
        o[nf] = __builtin_amdgcn_mfma_f32_16x16x32_bf16(pa, vf, o[nf], 0, 0, 0);
      }
    }
    __syncthreads();
  }

  float inv[4];
  #pragma unroll
  for (int j = 0; j < 4; j++) inv[j] = 1.f / l[j];
  u16* ob = out + (size_t)(b*1024 + q0 + wave*16)*4096 + h*128;
  #pragma unroll
  for (int nf = 0; nf < 8; nf++)
    #pragma unroll
    for (int j = 0; j < 4; j++) {
      int rr = (lane >> 4)*4 + j;
      int cc = nf*16 + (lane & 15);
      ob[(size_t)rr*4096 + cc] = f2bf(o[nf][j] * inv[j]);
    }
}

// ---------------- driver ----------------
extern "C" void kernel_launch(void* const* d_in, const int* in_sizes, int n_in,
                              void* d_out, int out_size, void* d_ws, size_t ws_size,
                              hipStream_t stream) {
  (void)in_sizes; (void)n_in; (void)out_size;
  const float* hidden = (const float*)d_in[0];
  const float* Wq  = (const float*)d_in[3];
  const float* Wk  = (const float*)d_in[4];
  const float* Wv  = (const float*)d_in[5];
  const float* Wo  = (const float*)d_in[6];
  const float* ln1 = (const float*)d_in[7];
  const float* ln2 = (const float*)d_in[8];
  const float* Wg  = (const float*)d_in[9];
  const float* Wu  = (const float*)d_in[10];
  const float* Wd  = (const float*)d_in[11];
  float* out = (float*)d_out;

  hipFuncSetAttribute((const void*)gemm256<4096,0>,  hipFuncAttributeMaxDynamicSharedMemorySize, 131072);
  hipFuncSetAttribute((const void*)gemm256<4096,1>,  hipFuncAttributeMaxDynamicSharedMemorySize, 131072);
  hipFuncSetAttribute((const void*)gemm256<4096,3>,  hipFuncAttributeMaxDynamicSharedMemorySize, 131072);
  hipFuncSetAttribute((const void*)gemm256<11008,1>, hipFuncAttributeMaxDynamicSharedMemorySize, 131072);

  char* ws = (char*)d_ws;
  size_t off = 0;
  auto alloc = [&](size_t b) { char* p = ws + off; off += (b + 4095) & ~(size_t)4095; return p; };

  u16*  wqkvT = (u16*)alloc(50331648);   // [6144][4096] bf16: wq | wk | wv
  u16*  woT   = (u16*)alloc(33554432);
  (void)alloc(8388608);                  // pad: lets wdT (86 MiB) alias wqkvT+woT+pad
  u16*  wguT  = (u16*)alloc(180355072);  // [22016][4096] interleaved gate/up (64-row = 32g+32u)
  u16*  h1    = (u16*)alloc(33554432);
  u16*  qb    = (u16*)alloc(33554432);
  u16*  kvb   = (u16*)alloc(16777216);   // [4096 tok][2048]: k | v
  u16*  vtb   = (u16*)alloc(8388608);
  float* hmid = (float*)alloc(67108864);
  u16*  gb    = (u16*)alloc(90177536);   // act [4096][11008] bf16
  if (off > ws_size) return;             // ws too small -> fail visibly

  u16* wqT  = wqkvT;
  u16* wkvT = wqkvT + 16777216;
  u16* wkT  = wkvT;
  u16* wvT  = wkvT + 4194304;
  u16* wdT  = wqkvT;                     // aliases wqkvT+woT+pad, both dead by gateup time
  CJob Jq{Wq, wqT, 4096, 4096, 4096, 0}, Jk{Wk, wkT, 4096, 1024, 1024, 0}, Jv{Wv, wvT, 4096, 1024, 1024, 0};
  CJob Jo{Wo, woT, 4096, 4096, 4096, 0};
  CJob Jg{Wg, wguT, 4096, 11008, 11008, 1}, Ju{Wu, wguT, 4096, 11008, 11008, 2};

  dim3 blk(256);
  conv3<<<2048, blk, 0, stream>>>(Jq, Jk, Jv);
  rmsnorm_kernel<<<4096, blk, 0, stream>>>(hidden, ln1, h1);
  gemm256<4096,0><<<256, 512, 131072, stream>>>(h1, wqT, qb, nullptr, 4096, 4096, 256,
                                                nullptr, nullptr, 0, 0, 0, 0);
  gemm_bt<0><<<512, blk, 0, stream>>>(h1, wkvT, kvb, nullptr, nullptr, 4096, 2048, 4096);
  rope_kernel<<<4096, blk, 0, stream>>>(qb, kvb, 2048);
  vtrans<<<dim3(4, 32, 32), dim3(32, 8), 0, stream>>>(kvb + 1024, vtb, 2048);
  // attention + hosted conversions of Wo (plain), Wg/Wu (interleaved into wguT)
  attn_kernel<<<2048 + 1024, blk, 0, stream>>>(qb, kvb, vtb, h1, Jo, Jg, Ju, 2048);
  gemm256<4096,1><<<256, 512, 131072, stream>>>(h1, woT, hmid, hidden, 4096, 4096, 256,
                                                nullptr, nullptr, 0, 0, 0, 0);
  rmsnorm_kernel<<<4096, blk, 0, stream>>>(hmid, ln2, qb);
  // merged gate+up GEMM (N-rows 22016 -> act [4096][11008]) + hosted Wd conversion
  gemm256<4096,3><<<1376 + 344, 512, 131072, stream>>>(qb, wguT, gb, nullptr, 4096, 11008, 1376,
                                                       Wd, wdT, 11008, 4096, 11008, 0);
  gemm256<11008,1><<<256, 512, 131072, stream>>>(gb, wdT, out, hmid, 4096, 4096, 256,
                                                 nullptr, nullptr, 0, 0, 0, 0);
}